// Round 13
// baseline (63.758 us; speedup 1.0000x reference)
//
#include <hip/hip_runtime.h>

#define EPS   1e-5f
#define NB    16
#define NS    2048
#define ND    768
#define NK    64
#define NPB   (NS * ND)      /* 1572864 elems per batch */

typedef __attribute__((ext_vector_type(8))) short short8;
typedef __attribute__((ext_vector_type(4))) unsigned short ushort4v;
typedef __attribute__((ext_vector_type(4))) float f32x4;

// lgkm-only barrier (proven R8): syncs LDS without draining vmcnt.
#define LGKM_BAR() do {                                      \
    asm volatile("s_waitcnt lgkmcnt(0)" ::: "memory");       \
    __builtin_amdgcn_sched_barrier(0);                       \
    __builtin_amdgcn_s_barrier();                            \
} while (0)

static __device__ __forceinline__ short f2bf(float f) {
    unsigned u = __builtin_bit_cast(unsigned, f);
    u += 0x7fffu + ((u >> 16) & 1u);   // round-to-nearest-even
    return (short)(u >> 16);
}
static __device__ __forceinline__ float bf2f(unsigned short h) {
    return __builtin_bit_cast(float, (unsigned)h << 16);
}

// ---------------------------------------------------------------------------
// Kernel 1: per-batch partial sums (NO atomics) + weight prep.  (R8 verbatim)
// ---------------------------------------------------------------------------
__global__ __launch_bounds__(256) void prep_reduce(
    const float* __restrict__ x, const float* __restrict__ W_up,
    const float* __restrict__ W_down, const float* __restrict__ W_ln,
    const float* __restrict__ b_ln, float2* __restrict__ stats_p,
    float* __restrict__ c1, float* __restrict__ c2,
    short* __restrict__ wdp, short* __restrict__ wub)
{
    __shared__ float red[8];
    const int bid = blockIdx.x, tid = threadIdx.x;
    const int wid = tid >> 6, lane = tid & 63;

    if (bid < 1024) {
        const int b = bid >> 6;
        const int chunk = bid & 63;
        const f32x4* xv = (const f32x4*)(x + (size_t)b * NPB + (size_t)chunk * (NPB / 64));
        float s = 0.f, ss = 0.f;
        #pragma unroll 8
        for (int i = tid; i < NPB / 64 / 4; i += 256) {
            f32x4 v = xv[i];
            s  += v[0] + v[1] + v[2] + v[3];
            ss += v[0]*v[0] + v[1]*v[1] + v[2]*v[2] + v[3]*v[3];
        }
        #pragma unroll
        for (int off = 32; off > 0; off >>= 1) {
            s  += __shfl_down(s, off, 64);
            ss += __shfl_down(ss, off, 64);
        }
        if (lane == 0) stats_p[bid * 4 + wid] = make_float2(s, ss);
    } else if (bid < 1088) {
        const int k = bid - 1024;
        float pc1 = 0.f, pc2 = 0.f;
        #pragma unroll
        for (int d = tid; d < ND; d += 256) {
            float wl = W_ln[d], wd = W_down[k * ND + d], bl = b_ln[d];
            wdp[k * ND + d] = f2bf(wl * wd);
            pc1 += wl * wd;
            pc2 += bl * wd;
        }
        #pragma unroll
        for (int off = 32; off > 0; off >>= 1) {
            pc1 += __shfl_down(pc1, off, 64);
            pc2 += __shfl_down(pc2, off, 64);
        }
        if (lane == 0) { red[wid] = pc1; red[4 + wid] = pc2; }
        __syncthreads();
        if (tid == 0) c1[k] = red[0] + red[1] + red[2] + red[3];
        if (tid == 1) c2[k] = red[4] + red[5] + red[6] + red[7];
    } else {
        const int i = (bid - 1088) * 256 + tid;   // exactly covers 49152
        wub[i] = f2bf(W_up[i]);
    }
}

// ---------------------------------------------------------------------------
// Kernel 2: fused LN + down-proj + ReLU + up-proj + residual.
// TILE-PAIR pipeline on the R12 structure: grid 256 (1 block/CU, single
// round); each block runs two 64-row tiles. Tile-1's x staging is issued
// inside tile-0's GEMM2 loop into x-chunk regions tile-0 has finished
// residual-reading (chunk c dead after dcg=3c+2): c0@w=2, c1@w=3, c2@w=5,
// c3 post-loop — tile-1's read phase streams under tile-0's write phase.
// All staging/compute/epilogue formulas byte-identical R12.
// LDS map (145 KiB, 1 block/CU):
//  [0,98304)        x bf16, 4 chunks x (64 rows x 384B, XOR-swizzled)
//  [98304,131072)   wub dbuf 2x16384
//  [131072,148480)  union{ h (64x128B, first) | stg (4 waves x 16x68 f32) }
// ---------------------------------------------------------------------------
__global__ __launch_bounds__(256) void fused_pair(
    const float* __restrict__ x, const short* __restrict__ wdp,
    const short* __restrict__ wub, const float* __restrict__ c1,
    const float* __restrict__ c2, const float2* __restrict__ stats_p,
    float* __restrict__ out)
{
    __shared__ __align__(16) char lds[148480];

    const int tid  = threadIdx.x;
    const int wid  = tid >> 6;
    const int lane = tid & 63;
    const int r    = lane & 15;        // MFMA row (A) / col (B,D)
    const int g    = lane >> 4;        // k-group
    const int sw   = (r & 7) << 4;     // read-side XOR swizzle
    const int rb0  = blockIdx.x * 128;          // tile-0 first row
    const int rb1  = rb0 + 64;                  // tile-1 first row
    const int b    = blockIdx.x >> 4;  // 16 blocks per batch

    char* const XB  = lds;             // x tile (4 chunk regions)
    char* const WB  = lds + 98304;     // wub dbuf
    char* const HS  = lds + 131072;    // h / stg overlay

    // ---- x staging into persistent chunk c (R12 proven formulas) -----------
    auto x_stage = [&](int c, int rb) {
        char* dst = XB + c * 24576;
        #pragma unroll
        for (int i = 0; i < 6; ++i) {
            int idx = i * 256 + tid;               // [0,1536)
            int row = idx / 24, u = idx % 24;
            const float* src = x + (size_t)(rb + row) * ND + c * 192 + u * 8;
            f32x4 a0 = *(const f32x4*)(src);
            f32x4 a1 = *(const f32x4*)(src + 4);
            short8 h8;
            h8[0]=f2bf(a0[0]); h8[1]=f2bf(a0[1]); h8[2]=f2bf(a0[2]); h8[3]=f2bf(a0[3]);
            h8[4]=f2bf(a1[0]); h8[5]=f2bf(a1[1]); h8[6]=f2bf(a1[2]); h8[7]=f2bf(a1[3]);
            *(short8*)(dst + row * 384 + ((u * 16) ^ ((row & 7) << 4))) = h8;
        }
    };

    // ---- tile-0 chunk 0 loads start immediately ----------------------------
    x_stage(0, rb0);

    // ---- fold the 256 per-wave partials for this batch (under staging) ----
    float s = 0.f, ss = 0.f;
    #pragma unroll
    for (int i = 0; i < 4; ++i) {
        float2 sp = stats_p[b * 256 + i * 64 + lane];
        s += sp.x; ss += sp.y;
    }
    #pragma unroll
    for (int off = 32; off > 0; off >>= 1) {
        s  += __shfl_xor(s, off, 64);
        ss += __shfl_xor(ss, off, 64);
    }
    const float invN = 1.f / (float)NPB;
    const float mu  = s * invN;
    const float var = ss * invN - mu * mu;
    const float rs  = rsqrtf(var + EPS);

    // ---- wdp col-stripe -> registers (R11/R12 proven) ----------------------
    short8 bw[24];
    {
        const short* wr = wdp + (wid * 16 + r) * ND + g * 8;
        #pragma unroll
        for (int kk = 0; kk < 24; ++kk)
            bw[kk] = *(const short8*)(wr + kk * 32);
    }

    // ---- GEMM1 compute on chunk c (R12 proven) -----------------------------
    f32x4 acc[4];
    #pragma unroll
    for (int rt = 0; rt < 4; ++rt)
        #pragma unroll
        for (int q = 0; q < 4; ++q) acc[rt][q] = 0.f;

    auto g1_compute = [&](int c) {
        const char* X = XB + c * 24576;
        #pragma unroll
        for (int kk2 = 0; kk2 < 6; ++kk2) {
            const int kk = c * 6 + kk2;
            #pragma unroll
            for (int rt = 0; rt < 4; ++rt) {
                short8 af = *(const short8*)(X + (rt * 16 + r) * 384
                                               + ((kk2 * 64 + g * 16) ^ sw));
                acc[rt] = __builtin_amdgcn_mfma_f32_16x16x32_bf16(af, bw[kk], acc[rt], 0, 0, 0);
            }
        }
    };

    // ---- wub staging helpers (R12 proven) ----------------------------------
    auto wub_load = [&](int w, short8* v) {
        #pragma unroll
        for (int i = 0; i < 4; ++i) {
            int idx = i * 256 + tid;               // [0,1024)
            int row = idx >> 3, u = idx & 7;
            v[i] = *(const short8*)(wub + (w * 128 + row) * 64 + u * 8);
        }
    };
    auto wub_write = [&](int p, const short8* v) {
        char* dst = WB + p * 16384;
        #pragma unroll
        for (int i = 0; i < 4; ++i) {
            int idx = i * 256 + tid;
            int row = idx >> 3, u = idx & 7;
            *(short8*)(dst + row * 128 + ((u * 16) ^ ((row & 7) << 4))) = v[i];
        }
    };

    // ---- epilogue-1 + GEMM2 for one tile; optionally prefetch next tile's x
    const int erow = lane >> 4;        // 0..3   (full-line epilogue mapping)
    const int ecol = (lane & 15) * 4;  // 0..60

    auto do_tail = [&](int rb, int rb_next) {
        // epilogue 1: z = rs*acc + kb; relu; -> block-shared h (R12 proven)
        {
            const int colg = wid * 16 + r;
            const float kb = c2[colg] - rs * mu * c1[colg];
            #pragma unroll
            for (int rt = 0; rt < 4; ++rt) {
                #pragma unroll
                for (int reg = 0; reg < 4; ++reg) {
                    float z = fmaf(rs, acc[rt][reg], kb);
                    const int hrow = rt * 16 + g * 4 + reg;
                    *(short*)(HS + hrow * 128
                              + ((colg * 2) ^ ((hrow & 7) << 4))) = f2bf(fmaxf(z, 0.f));
                }
            }
        }
        LGKM_BAR();                    // h complete (+ pending wub buf0)

        const char* H = HS + (wid * 16 + r) * 128;
        short8 a2_0 = *(const short8*)(H + ((g * 16) ^ sw));
        short8 a2_1 = *(const short8*)(H + ((64 + g * 16) ^ sw));
        LGKM_BAR();                    // all a2 reads done; h region reusable

        float* outr = out + (size_t)(rb + wid * 16) * ND;
        float* S = (float*)(HS) + wid * 1088;   // 16x68 f32 per wave (overlay)

        for (int w = 0; w < 6; ++w) {
            if (rb_next >= 0) {        // tile-pair prefetch into dead x chunks
                if      (w == 2) x_stage(0, rb_next);
                else if (w == 3) x_stage(1, rb_next);
                else if (w == 5) x_stage(2, rb_next);
            }
            short8 u[4];
            if (w < 5) wub_load(w + 1, u);               // issue early (T14)
            const char* W = WB + (w & 1) * 16384;
            #pragma unroll
            for (int dq = 0; dq < 2; ++dq) {
                const int dcg = w * 2 + dq;                    // global 64-col chunk
                f32x4 acc2[4];
                #pragma unroll
                for (int cf = 0; cf < 4; ++cf)
                    #pragma unroll
                    for (int q = 0; q < 4; ++q) acc2[cf][q] = 0.f;
                #pragma unroll
                for (int cf = 0; cf < 4; ++cf) {
                    const int dl = dq * 64 + cf * 16 + r;      // local wub row
                    short8 b0 = *(const short8*)(W + dl * 128 + ((g * 16) ^ sw));
                    short8 b1 = *(const short8*)(W + dl * 128 + ((64 + g * 16) ^ sw));
                    acc2[cf] = __builtin_amdgcn_mfma_f32_16x16x32_bf16(a2_0, b0, acc2[cf], 0, 0, 0);
                    acc2[cf] = __builtin_amdgcn_mfma_f32_16x16x32_bf16(a2_1, b1, acc2[cf], 0, 0, 0);
                }
                // transpose C/D layout -> row-major via per-wave LDS (stride 68)
                #pragma unroll
                for (int cf = 0; cf < 4; ++cf)
                    #pragma unroll
                    for (int reg = 0; reg < 4; ++reg)
                        S[(g * 4 + reg) * 68 + cf * 16 + r] = acc2[cf][reg];
                // residual from LDS x (bf16) + single f32x4 nt store per j
                #pragma unroll
                for (int j = 0; j < 4; ++j) {
                    const int row   = j * 4 + erow;            // 0..15 (wave-local)
                    f32x4 v = *(const f32x4*)(S + row * 68 + ecol);
                    const int col   = dcg * 64 + ecol;
                    const int row_l = wid * 16 + row;          // block-local row
                    const int c     = col / 192;
                    const int wb    = (col - c * 192) * 2;     // byte offset in chunk row
                    const char* xa  = XB + c * 24576 + row_l * 384
                                      + (((wb & ~15) ^ ((row_l & 7) << 4)) | (wb & 15));
                    ushort4v hx = *(const ushort4v*)xa;
                    v[0] += bf2f(hx[0]); v[1] += bf2f(hx[1]);
                    v[2] += bf2f(hx[2]); v[3] += bf2f(hx[3]);
                    __builtin_nontemporal_store(v, (f32x4*)(outr + (size_t)row * ND + col));
                }
            }
            if (w < 5) wub_write((w + 1) & 1, u);        // write late (T14)
            LGKM_BAR();
        }
    };

    // ======================= TILE 0 =======================
    LGKM_BAR();
    g1_compute(0);
    x_stage(1, rb0);
    LGKM_BAR();
    g1_compute(1);
    x_stage(2, rb0);
    LGKM_BAR();
    g1_compute(2);
    x_stage(3, rb0);
    LGKM_BAR();
    {
        short8 u0[4];
        wub_load(0, u0);
        g1_compute(3);
        wub_write(0, u0);
    }
    do_tail(rb0, rb1);                 // GEMM2(t0) with t1 x-prefetch

    // ======================= TILE 1 =======================
    #pragma unroll
    for (int rt = 0; rt < 4; ++rt)
        #pragma unroll
        for (int q = 0; q < 4; ++q) acc[rt][q] = 0.f;

    x_stage(3, rb1);                   // last missing chunk; flies under compute
    g1_compute(0);
    g1_compute(1);
    g1_compute(2);
    LGKM_BAR();                        // t1 chunk-3 ds_writes complete
    {
        short8 u0[4];
        wub_load(0, u0);
        g1_compute(3);
        wub_write(0, u0);
    }
    do_tail(rb1, -1);                  // GEMM2(t1), no prefetch
}

// ---------------------------------------------------------------------------
extern "C" void kernel_launch(void* const* d_in, const int* in_sizes, int n_in,
                              void* d_out, int out_size, void* d_ws, size_t ws_size,
                              hipStream_t stream)
{
    const float* x      = (const float*)d_in[0];
    const float* W_up   = (const float*)d_in[1];
    // d_in[2] = b_up   (unused by reference)
    const float* W_down = (const float*)d_in[3];
    // d_in[4] = b_down (unused by reference)
    const float* W_ln   = (const float*)d_in[5];
    const float* b_ln   = (const float*)d_in[6];
    float* out = (float*)d_out;

    char* ws = (char*)d_ws;
    float2* stats_p = (float2*)ws;                 // 4096 x float2 = 32 KiB
    float*  c1      = (float*)(ws + 32768);        // 64 f32
    float*  c2      = (float*)(ws + 33024);        // 64 f32
    short*  wdp     = (short*)(ws + 33280);        // bf16 [64][768] = 96 KiB
    short*  wub     = (short*)(ws + 131584);       // bf16 [768][64] = 96 KiB

    prep_reduce<<<1280, 256, 0, stream>>>(x, W_up, W_down, W_ln, b_ln,
                                          stats_p, c1, c2, wdp, wub);
    fused_pair<<<256, 256, 0, stream>>>(x, wdp, wub, c1, c2, stats_p, out);
}

// Round 14
// 58.754 us; speedup vs baseline: 1.0852x; 1.0852x over previous
//
#include <hip/hip_runtime.h>

#define EPS   1e-5f
#define NB    16
#define NS    2048
#define ND    768
#define NK    64
#define NPB   (NS * ND)      /* 1572864 elems per batch */

typedef __attribute__((ext_vector_type(8))) short short8;
typedef __attribute__((ext_vector_type(4))) unsigned short ushort4v;
typedef __attribute__((ext_vector_type(4))) float f32x4;

// lgkm-only barrier (proven R8): syncs LDS without draining vmcnt.
#define LGKM_BAR() do {                                      \
    asm volatile("s_waitcnt lgkmcnt(0)" ::: "memory");       \
    __builtin_amdgcn_sched_barrier(0);                       \
    __builtin_amdgcn_s_barrier();                            \
} while (0)

static __device__ __forceinline__ short f2bf(float f) {
    unsigned u = __builtin_bit_cast(unsigned, f);
    u += 0x7fffu + ((u >> 16) & 1u);   // round-to-nearest-even
    return (short)(u >> 16);
}
static __device__ __forceinline__ float bf2f(unsigned short h) {
    return __builtin_bit_cast(float, (unsigned)h << 16);
}

// ---------------------------------------------------------------------------
// Kernel 1: per-batch partial sums (NO atomics) + weight prep.  (R8 verbatim)
// ---------------------------------------------------------------------------
__global__ __launch_bounds__(256) void prep_reduce(
    const float* __restrict__ x, const float* __restrict__ W_up,
    const float* __restrict__ W_down, const float* __restrict__ W_ln,
    const float* __restrict__ b_ln, float2* __restrict__ stats_p,
    float* __restrict__ c1, float* __restrict__ c2,
    short* __restrict__ wdp, short* __restrict__ wub)
{
    __shared__ float red[8];
    const int bid = blockIdx.x, tid = threadIdx.x;
    const int wid = tid >> 6, lane = tid & 63;

    if (bid < 1024) {
        const int b = bid >> 6;
        const int chunk = bid & 63;
        const f32x4* xv = (const f32x4*)(x + (size_t)b * NPB + (size_t)chunk * (NPB / 64));
        float s = 0.f, ss = 0.f;
        #pragma unroll 8
        for (int i = tid; i < NPB / 64 / 4; i += 256) {
            f32x4 v = xv[i];
            s  += v[0] + v[1] + v[2] + v[3];
            ss += v[0]*v[0] + v[1]*v[1] + v[2]*v[2] + v[3]*v[3];
        }
        #pragma unroll
        for (int off = 32; off > 0; off >>= 1) {
            s  += __shfl_down(s, off, 64);
            ss += __shfl_down(ss, off, 64);
        }
        if (lane == 0) stats_p[bid * 4 + wid] = make_float2(s, ss);
    } else if (bid < 1088) {
        const int k = bid - 1024;
        float pc1 = 0.f, pc2 = 0.f;
        #pragma unroll
        for (int d = tid; d < ND; d += 256) {
            float wl = W_ln[d], wd = W_down[k * ND + d], bl = b_ln[d];
            wdp[k * ND + d] = f2bf(wl * wd);
            pc1 += wl * wd;
            pc2 += bl * wd;
        }
        #pragma unroll
        for (int off = 32; off > 0; off >>= 1) {
            pc1 += __shfl_down(pc1, off, 64);
            pc2 += __shfl_down(pc2, off, 64);
        }
        if (lane == 0) { red[wid] = pc1; red[4 + wid] = pc2; }
        __syncthreads();
        if (tid == 0) c1[k] = red[0] + red[1] + red[2] + red[3];
        if (tid == 1) c2[k] = red[4] + red[5] + red[6] + red[7];
    } else {
        const int i = (bid - 1088) * 256 + tid;   // exactly covers 49152
        wub[i] = f2bf(W_up[i]);
    }
}

// ---------------------------------------------------------------------------
// Kernel 2: fused LN + down-proj + ReLU + up-proj + residual.  (R12 verbatim
// except ONE delta: epilogue stores are plain cached f32x4 stores, not
// nontemporal — stores complete at L2, freeing vmcnt slots ~5x faster and
// letting HBM write-back overlap subsequent compute / next block.)
// LDS map (145 KiB -> 1 block/CU, 8 waves):
//  [0,98304)        x bf16, 4 chunks x (64 rows x 384B, XOR-swizzled)
//  [98304,131072)   wub dbuf 2x16384
//  [131072,148480)  union{ h (64x128B, first) | stg (4 waves x 16x68 f32) }
// ---------------------------------------------------------------------------
__global__ __launch_bounds__(256) void fused_main(
    const float* __restrict__ x, const short* __restrict__ wdp,
    const short* __restrict__ wub, const float* __restrict__ c1,
    const float* __restrict__ c2, const float2* __restrict__ stats_p,
    float* __restrict__ out)
{
    __shared__ __align__(16) char lds[148480];

    const int tid  = threadIdx.x;
    const int wid  = tid >> 6;
    const int lane = tid & 63;
    const int r    = lane & 15;        // MFMA row (A) / col (B,D)
    const int g    = lane >> 4;        // k-group
    const int sw   = (r & 7) << 4;     // read-side XOR swizzle
    const int row0b = blockIdx.x * 64;          // block's first row
    const int row0  = row0b + wid * 16;         // this wave's GEMM2 rows
    const int b    = blockIdx.x >> 5;  // 32 blocks per batch

    char* const XB  = lds;             // x tile
    char* const WB  = lds + 98304;     // wub dbuf
    char* const HS  = lds + 131072;    // h / stg overlay

    // ---- fold the 256 per-wave partials for this batch (L2-hit) ----------
    float s = 0.f, ss = 0.f;
    #pragma unroll
    for (int i = 0; i < 4; ++i) {
        float2 sp = stats_p[b * 256 + i * 64 + lane];
        s += sp.x; ss += sp.y;
    }
    #pragma unroll
    for (int off = 32; off > 0; off >>= 1) {
        s  += __shfl_xor(s, off, 64);
        ss += __shfl_xor(ss, off, 64);
    }
    const float invN = 1.f / (float)NPB;
    const float mu  = s * invN;
    const float var = ss * invN - mu * mu;
    const float rs  = rsqrtf(var + EPS);

    // ---- wdp col-stripe -> registers (R11 proven; L2-hot, loaded once) ----
    short8 bw[24];
    {
        const short* wr = wdp + (wid * 16 + r) * ND + g * 8;
        #pragma unroll
        for (int kk = 0; kk < 24; ++kk)
            bw[kk] = *(const short8*)(wr + kk * 32);
    }

    // ---- x staging into persistent chunk c (R7 proven formulas) -----------
    auto x_stage = [&](int c) {
        char* dst = XB + c * 24576;
        #pragma unroll
        for (int i = 0; i < 6; ++i) {
            int idx = i * 256 + tid;               // [0,1536)
            int row = idx / 24, u = idx % 24;
            const float* src = x + (size_t)(row0b + row) * ND + c * 192 + u * 8;
            f32x4 a0 = *(const f32x4*)(src);
            f32x4 a1 = *(const f32x4*)(src + 4);
            short8 h8;
            h8[0]=f2bf(a0[0]); h8[1]=f2bf(a0[1]); h8[2]=f2bf(a0[2]); h8[3]=f2bf(a0[3]);
            h8[4]=f2bf(a1[0]); h8[5]=f2bf(a1[1]); h8[6]=f2bf(a1[2]); h8[7]=f2bf(a1[3]);
            *(short8*)(dst + row * 384 + ((u * 16) ^ ((row & 7) << 4))) = h8;
        }
    };

    // ---- GEMM1 compute on chunk c: all 64 rows x 6 k-steps (R12 proven) ---
    f32x4 acc[4] = {};
    auto g1_compute = [&](int c) {
        const char* X = XB + c * 24576;
        #pragma unroll
        for (int kk2 = 0; kk2 < 6; ++kk2) {
            const int kk = c * 6 + kk2;
            #pragma unroll
            for (int rt = 0; rt < 4; ++rt) {
                short8 af = *(const short8*)(X + (rt * 16 + r) * 384
                                               + ((kk2 * 64 + g * 16) ^ sw));
                acc[rt] = __builtin_amdgcn_mfma_f32_16x16x32_bf16(af, bw[kk], acc[rt], 0, 0, 0);
            }
        }
    };

    // chunk regions are disjoint: stage(c+1) may run before/while compute(c)
    x_stage(0);
    LGKM_BAR();
    g1_compute(0);
    x_stage(1);
    LGKM_BAR();
    g1_compute(1);
    x_stage(2);
    LGKM_BAR();
    g1_compute(2);
    x_stage(3);
    LGKM_BAR();

    // ---- wub staging helpers (R6 formulas, rebased) ------------------------
    auto wub_load = [&](int w, short8* v) {
        #pragma unroll
        for (int i = 0; i < 4; ++i) {
            int idx = i * 256 + tid;               // [0,1024)
            int row = idx >> 3, u = idx & 7;
            v[i] = *(const short8*)(wub + (w * 128 + row) * 64 + u * 8);
        }
    };
    auto wub_write = [&](int p, const short8* v) {
        char* dst = WB + p * 16384;
        #pragma unroll
        for (int i = 0; i < 4; ++i) {
            int idx = i * 256 + tid;
            int row = idx >> 3, u = idx & 7;
            *(short8*)(dst + row * 128 + ((u * 16) ^ ((row & 7) << 4))) = v[i];
        }
    };

    {
        short8 u0[4];
        wub_load(0, u0);
        g1_compute(3);
        wub_write(0, u0);
    }

    // ---- epilogue 1: z = rs*acc + kb; relu; -> block-shared h (R11 proven) -
    {
        const int colg = wid * 16 + r;
        const float kb = c2[colg] - rs * mu * c1[colg];
        #pragma unroll
        for (int rt = 0; rt < 4; ++rt) {
            #pragma unroll
            for (int reg = 0; reg < 4; ++reg) {
                float z = fmaf(rs, acc[rt][reg], kb);
                const int hrow = rt * 16 + g * 4 + reg;
                *(short*)(HS + hrow * 128
                          + ((colg * 2) ^ ((hrow & 7) << 4))) = f2bf(fmaxf(z, 0.f));
            }
        }
    }
    LGKM_BAR();                        // h + wub buf0 complete

    // ---- GEMM2 A-fragments (R11 proven), then guard h before stg overlay --
    const char* H = HS + (wid * 16 + r) * 128;
    short8 a2_0 = *(const short8*)(H + ((g * 16) ^ sw));
    short8 a2_1 = *(const short8*)(H + ((64 + g * 16) ^ sw));
    LGKM_BAR();                        // all a2 reads done; h region reusable

    float*    outr = out + (size_t)row0 * ND;
    const int erow = lane >> 4;        // 0..3   (full-line epilogue mapping)
    const int ecol = (lane & 15) * 4;  // 0..60
    float* S = (float*)(HS) + wid * 1088;   // 16x68 f32 per wave (overlay)

    for (int w = 0; w < 6; ++w) {
        short8 u[4];
        if (w < 5) wub_load(w + 1, u);               // issue early (T14)
        const char* W = WB + (w & 1) * 16384;
        #pragma unroll
        for (int dq = 0; dq < 2; ++dq) {
            const int dcg = w * 2 + dq;                    // global 64-col chunk
            f32x4 acc2[4] = {};
            #pragma unroll
            for (int cf = 0; cf < 4; ++cf) {
                const int dl = dq * 64 + cf * 16 + r;      // local wub row
                short8 b0 = *(const short8*)(W + dl * 128 + ((g * 16) ^ sw));
                short8 b1 = *(const short8*)(W + dl * 128 + ((64 + g * 16) ^ sw));
                acc2[cf] = __builtin_amdgcn_mfma_f32_16x16x32_bf16(a2_0, b0, acc2[cf], 0, 0, 0);
                acc2[cf] = __builtin_amdgcn_mfma_f32_16x16x32_bf16(a2_1, b1, acc2[cf], 0, 0, 0);
            }
            // transpose C/D layout -> row-major via per-wave LDS (stride 68)
            #pragma unroll
            for (int cf = 0; cf < 4; ++cf)
                #pragma unroll
                for (int reg = 0; reg < 4; ++reg)
                    S[(g * 4 + reg) * 68 + cf * 16 + r] = acc2[cf][reg];
            // residual from LDS x (bf16) + single CACHED f32x4 store per j
            #pragma unroll
            for (int j = 0; j < 4; ++j) {
                const int row   = j * 4 + erow;            // 0..15 (wave-local)
                f32x4 v = *(const f32x4*)(S + row * 68 + ecol);
                const int col   = dcg * 64 + ecol;
                const int row_l = wid * 16 + row;          // block-local row
                const int c     = col / 192;
                const int wb    = (col - c * 192) * 2;     // byte offset in chunk row
                const char* xa  = XB + c * 24576 + row_l * 384
                                  + (((wb & ~15) ^ ((row_l & 7) << 4)) | (wb & 15));
                ushort4v hx = *(const ushort4v*)xa;
                v[0] += bf2f(hx[0]); v[1] += bf2f(hx[1]);
                v[2] += bf2f(hx[2]); v[3] += bf2f(hx[3]);
                *(f32x4*)(outr + (size_t)row * ND + col) = v;   // cached store
            }
        }
        if (w < 5) wub_write((w + 1) & 1, u);        // write late (T14)
        LGKM_BAR();
    }
}

// ---------------------------------------------------------------------------
extern "C" void kernel_launch(void* const* d_in, const int* in_sizes, int n_in,
                              void* d_out, int out_size, void* d_ws, size_t ws_size,
                              hipStream_t stream)
{
    const float* x      = (const float*)d_in[0];
    const float* W_up   = (const float*)d_in[1];
    // d_in[2] = b_up   (unused by reference)
    const float* W_down = (const float*)d_in[3];
    // d_in[4] = b_down (unused by reference)
    const float* W_ln   = (const float*)d_in[5];
    const float* b_ln   = (const float*)d_in[6];
    float* out = (float*)d_out;

    char* ws = (char*)d_ws;
    float2* stats_p = (float2*)ws;                 // 4096 x float2 = 32 KiB
    float*  c1      = (float*)(ws + 32768);        // 64 f32
    float*  c2      = (float*)(ws + 33024);        // 64 f32
    short*  wdp     = (short*)(ws + 33280);        // bf16 [64][768] = 96 KiB
    short*  wub     = (short*)(ws + 131584);       // bf16 [768][64] = 96 KiB

    prep_reduce<<<1280, 256, 0, stream>>>(x, W_up, W_down, W_ln, b_ln,
                                          stats_p, c1, c2, wdp, wub);
    fused_main<<<512, 256, 0, stream>>>(x, wdp, wub, c1, c2, stats_p, out);
}

// Round 15
// 57.795 us; speedup vs baseline: 1.1032x; 1.0166x over previous
//
#include <hip/hip_runtime.h>

#define EPS   1e-5f
#define NB    16
#define NS    2048
#define ND    768
#define NK    64
#define NPB   (NS * ND)      /* 1572864 elems per batch */

typedef __attribute__((ext_vector_type(8))) short short8;
typedef __attribute__((ext_vector_type(4))) unsigned short ushort4v;
typedef __attribute__((ext_vector_type(4))) float f32x4;

// lgkm-only barrier (proven R8): syncs LDS without draining vmcnt.
#define LGKM_BAR() do {                                      \
    asm volatile("s_waitcnt lgkmcnt(0)" ::: "memory");       \
    __builtin_amdgcn_sched_barrier(0);                       \
    __builtin_amdgcn_s_barrier();                            \
} while (0)

static __device__ __forceinline__ short f2bf(float f) {
    unsigned u = __builtin_bit_cast(unsigned, f);
    u += 0x7fffu + ((u >> 16) & 1u);   // round-to-nearest-even
    return (short)(u >> 16);
}
static __device__ __forceinline__ float bf2f(unsigned short h) {
    return __builtin_bit_cast(float, (unsigned)h << 16);
}

// ---------------------------------------------------------------------------
// Kernel 1: per-batch partial sums (NO atomics) + weight prep.  (R8 verbatim)
// ---------------------------------------------------------------------------
__global__ __launch_bounds__(256) void prep_reduce(
    const float* __restrict__ x, const float* __restrict__ W_up,
    const float* __restrict__ W_down, const float* __restrict__ W_ln,
    const float* __restrict__ b_ln, float2* __restrict__ stats_p,
    float* __restrict__ c1, float* __restrict__ c2,
    short* __restrict__ wdp, short* __restrict__ wub)
{
    __shared__ float red[8];
    const int bid = blockIdx.x, tid = threadIdx.x;
    const int wid = tid >> 6, lane = tid & 63;

    if (bid < 1024) {
        const int b = bid >> 6;
        const int chunk = bid & 63;
        const f32x4* xv = (const f32x4*)(x + (size_t)b * NPB + (size_t)chunk * (NPB / 64));
        float s = 0.f, ss = 0.f;
        #pragma unroll 8
        for (int i = tid; i < NPB / 64 / 4; i += 256) {
            f32x4 v = xv[i];
            s  += v[0] + v[1] + v[2] + v[3];
            ss += v[0]*v[0] + v[1]*v[1] + v[2]*v[2] + v[3]*v[3];
        }
        #pragma unroll
        for (int off = 32; off > 0; off >>= 1) {
            s  += __shfl_down(s, off, 64);
            ss += __shfl_down(ss, off, 64);
        }
        if (lane == 0) stats_p[bid * 4 + wid] = make_float2(s, ss);
    } else if (bid < 1088) {
        const int k = bid - 1024;
        float pc1 = 0.f, pc2 = 0.f;
        #pragma unroll
        for (int d = tid; d < ND; d += 256) {
            float wl = W_ln[d], wd = W_down[k * ND + d], bl = b_ln[d];
            wdp[k * ND + d] = f2bf(wl * wd);
            pc1 += wl * wd;
            pc2 += bl * wd;
        }
        #pragma unroll
        for (int off = 32; off > 0; off >>= 1) {
            pc1 += __shfl_down(pc1, off, 64);
            pc2 += __shfl_down(pc2, off, 64);
        }
        if (lane == 0) { red[wid] = pc1; red[4 + wid] = pc2; }
        __syncthreads();
        if (tid == 0) c1[k] = red[0] + red[1] + red[2] + red[3];
        if (tid == 1) c2[k] = red[4] + red[5] + red[6] + red[7];
    } else {
        const int i = (bid - 1088) * 256 + tid;   // exactly covers 49152
        wub[i] = f2bf(W_up[i]);
    }
}

// ---------------------------------------------------------------------------
// Kernel 2: fused LN + down-proj + ReLU + up-proj + residual. (R12 verbatim,
// nt-stores restored — best measured configuration, 58.04us total.)
// x tile (64x768) persists in LDS as bf16 for the WHOLE kernel: staged once,
// serves GEMM1 A-frags AND the GEMM2 residual. wdp in registers. h block-
// shared; stg overlays h.
// LDS map (145 KiB -> 1 block/CU):
//  [0,98304)        x bf16, 4 chunks x (64 rows x 384B, XOR-swizzled)
//  [98304,131072)   wub dbuf 2x16384
//  [131072,148480)  union{ h (64x128B, first) | stg (4 waves x 16x68 f32) }
// ---------------------------------------------------------------------------
__global__ __launch_bounds__(256) void fused_main(
    const float* __restrict__ x, const short* __restrict__ wdp,
    const short* __restrict__ wub, const float* __restrict__ c1,
    const float* __restrict__ c2, const float2* __restrict__ stats_p,
    float* __restrict__ out)
{
    __shared__ __align__(16) char lds[148480];

    const int tid  = threadIdx.x;
    const int wid  = tid >> 6;
    const int lane = tid & 63;
    const int r    = lane & 15;        // MFMA row (A) / col (B,D)
    const int g    = lane >> 4;        // k-group
    const int sw   = (r & 7) << 4;     // read-side XOR swizzle
    const int row0b = blockIdx.x * 64;          // block's first row
    const int row0  = row0b + wid * 16;         // this wave's GEMM2 rows
    const int b    = blockIdx.x >> 5;  // 32 blocks per batch

    char* const XB  = lds;             // x tile
    char* const WB  = lds + 98304;     // wub dbuf
    char* const HS  = lds + 131072;    // h / stg overlay

    // ---- fold the 256 per-wave partials for this batch (L2-hit) ----------
    float s = 0.f, ss = 0.f;
    #pragma unroll
    for (int i = 0; i < 4; ++i) {
        float2 sp = stats_p[b * 256 + i * 64 + lane];
        s += sp.x; ss += sp.y;
    }
    #pragma unroll
    for (int off = 32; off > 0; off >>= 1) {
        s  += __shfl_xor(s, off, 64);
        ss += __shfl_xor(ss, off, 64);
    }
    const float invN = 1.f / (float)NPB;
    const float mu  = s * invN;
    const float var = ss * invN - mu * mu;
    const float rs  = rsqrtf(var + EPS);

    // ---- wdp col-stripe -> registers (L2-hot, loaded once) ----------------
    short8 bw[24];
    {
        const short* wr = wdp + (wid * 16 + r) * ND + g * 8;
        #pragma unroll
        for (int kk = 0; kk < 24; ++kk)
            bw[kk] = *(const short8*)(wr + kk * 32);
    }

    // ---- x staging into persistent chunk c --------------------------------
    auto x_stage = [&](int c) {
        char* dst = XB + c * 24576;
        #pragma unroll
        for (int i = 0; i < 6; ++i) {
            int idx = i * 256 + tid;               // [0,1536)
            int row = idx / 24, u = idx % 24;
            const float* src = x + (size_t)(row0b + row) * ND + c * 192 + u * 8;
            f32x4 a0 = *(const f32x4*)(src);
            f32x4 a1 = *(const f32x4*)(src + 4);
            short8 h8;
            h8[0]=f2bf(a0[0]); h8[1]=f2bf(a0[1]); h8[2]=f2bf(a0[2]); h8[3]=f2bf(a0[3]);
            h8[4]=f2bf(a1[0]); h8[5]=f2bf(a1[1]); h8[6]=f2bf(a1[2]); h8[7]=f2bf(a1[3]);
            *(short8*)(dst + row * 384 + ((u * 16) ^ ((row & 7) << 4))) = h8;
        }
    };

    // ---- GEMM1 compute on chunk c: all 64 rows x 6 k-steps ----------------
    f32x4 acc[4] = {};
    auto g1_compute = [&](int c) {
        const char* X = XB + c * 24576;
        #pragma unroll
        for (int kk2 = 0; kk2 < 6; ++kk2) {
            const int kk = c * 6 + kk2;
            #pragma unroll
            for (int rt = 0; rt < 4; ++rt) {
                short8 af = *(const short8*)(X + (rt * 16 + r) * 384
                                               + ((kk2 * 64 + g * 16) ^ sw));
                acc[rt] = __builtin_amdgcn_mfma_f32_16x16x32_bf16(af, bw[kk], acc[rt], 0, 0, 0);
            }
        }
    };

    // chunk regions are disjoint: stage(c+1) may run before/while compute(c)
    x_stage(0);
    LGKM_BAR();
    g1_compute(0);
    x_stage(1);
    LGKM_BAR();
    g1_compute(1);
    x_stage(2);
    LGKM_BAR();
    g1_compute(2);
    x_stage(3);
    LGKM_BAR();

    // ---- wub staging helpers ----------------------------------------------
    auto wub_load = [&](int w, short8* v) {
        #pragma unroll
        for (int i = 0; i < 4; ++i) {
            int idx = i * 256 + tid;               // [0,1024)
            int row = idx >> 3, u = idx & 7;
            v[i] = *(const short8*)(wub + (w * 128 + row) * 64 + u * 8);
        }
    };
    auto wub_write = [&](int p, const short8* v) {
        char* dst = WB + p * 16384;
        #pragma unroll
        for (int i = 0; i < 4; ++i) {
            int idx = i * 256 + tid;
            int row = idx >> 3, u = idx & 7;
            *(short8*)(dst + row * 128 + ((u * 16) ^ ((row & 7) << 4))) = v[i];
        }
    };

    {
        short8 u0[4];
        wub_load(0, u0);
        g1_compute(3);
        wub_write(0, u0);
    }

    // ---- epilogue 1: z = rs*acc + kb; relu; -> block-shared h (swizzled) --
    {
        const int colg = wid * 16 + r;
        const float kb = c2[colg] - rs * mu * c1[colg];
        #pragma unroll
        for (int rt = 0; rt < 4; ++rt) {
            #pragma unroll
            for (int reg = 0; reg < 4; ++reg) {
                float z = fmaf(rs, acc[rt][reg], kb);
                const int hrow = rt * 16 + g * 4 + reg;
                *(short*)(HS + hrow * 128
                          + ((colg * 2) ^ ((hrow & 7) << 4))) = f2bf(fmaxf(z, 0.f));
            }
        }
    }
    LGKM_BAR();                        // h + wub buf0 complete

    // ---- GEMM2 A-fragments, then guard h before stg overlay ---------------
    const char* H = HS + (wid * 16 + r) * 128;
    short8 a2_0 = *(const short8*)(H + ((g * 16) ^ sw));
    short8 a2_1 = *(const short8*)(H + ((64 + g * 16) ^ sw));
    LGKM_BAR();                        // all a2 reads done; h region reusable

    float*    outr = out + (size_t)row0 * ND;
    const int erow = lane >> 4;        // 0..3   (full-line epilogue mapping)
    const int ecol = (lane & 15) * 4;  // 0..60
    float* S = (float*)(HS) + wid * 1088;   // 16x68 f32 per wave (overlay)

    for (int w = 0; w < 6; ++w) {
        short8 u[4];
        if (w < 5) wub_load(w + 1, u);               // issue early (T14)
        const char* W = WB + (w & 1) * 16384;
        #pragma unroll
        for (int dq = 0; dq < 2; ++dq) {
            const int dcg = w * 2 + dq;                    // global 64-col chunk
            f32x4 acc2[4] = {};
            #pragma unroll
            for (int cf = 0; cf < 4; ++cf) {
                const int dl = dq * 64 + cf * 16 + r;      // local wub row
                short8 b0 = *(const short8*)(W + dl * 128 + ((g * 16) ^ sw));
                short8 b1 = *(const short8*)(W + dl * 128 + ((64 + g * 16) ^ sw));
                acc2[cf] = __builtin_amdgcn_mfma_f32_16x16x32_bf16(a2_0, b0, acc2[cf], 0, 0, 0);
                acc2[cf] = __builtin_amdgcn_mfma_f32_16x16x32_bf16(a2_1, b1, acc2[cf], 0, 0, 0);
            }
            // transpose C/D layout -> row-major via per-wave LDS (stride 68)
            #pragma unroll
            for (int cf = 0; cf < 4; ++cf)
                #pragma unroll
                for (int reg = 0; reg < 4; ++reg)
                    S[(g * 4 + reg) * 68 + cf * 16 + r] = acc2[cf][reg];
            // residual from LDS x (bf16) + single f32x4 nt store per j
            #pragma unroll
            for (int j = 0; j < 4; ++j) {
                const int row   = j * 4 + erow;            // 0..15 (wave-local)
                f32x4 v = *(const f32x4*)(S + row * 68 + ecol);
                const int col   = dcg * 64 + ecol;
                const int row_l = wid * 16 + row;          // block-local row
                const int c     = col / 192;
                const int wb    = (col - c * 192) * 2;     // byte offset in chunk row
                const char* xa  = XB + c * 24576 + row_l * 384
                                  + (((wb & ~15) ^ ((row_l & 7) << 4)) | (wb & 15));
                ushort4v hx = *(const ushort4v*)xa;
                v[0] += bf2f(hx[0]); v[1] += bf2f(hx[1]);
                v[2] += bf2f(hx[2]); v[3] += bf2f(hx[3]);
                __builtin_nontemporal_store(v, (f32x4*)(outr + (size_t)row * ND + col));
            }
        }
        if (w < 5) wub_write((w + 1) & 1, u);        // write late (T14)
        LGKM_BAR();
    }
}

// ---------------------------------------------------------------------------
extern "C" void kernel_launch(void* const* d_in, const int* in_sizes, int n_in,
                              void* d_out, int out_size, void* d_ws, size_t ws_size,
                              hipStream_t stream)
{
    const float* x      = (const float*)d_in[0];
    const float* W_up   = (const float*)d_in[1];
    // d_in[2] = b_up   (unused by reference)
    const float* W_down = (const float*)d_in[3];
    // d_in[4] = b_down (unused by reference)
    const float* W_ln   = (const float*)d_in[5];
    const float* b_ln   = (const float*)d_in[6];
    float* out = (float*)d_out;

    char* ws = (char*)d_ws;
    float2* stats_p = (float2*)ws;                 // 4096 x float2 = 32 KiB
    float*  c1      = (float*)(ws + 32768);        // 64 f32
    float*  c2      = (float*)(ws + 33024);        // 64 f32
    short*  wdp     = (short*)(ws + 33280);        // bf16 [64][768] = 96 KiB
    short*  wub     = (short*)(ws + 131584);       // bf16 [768][64] = 96 KiB

    prep_reduce<<<1280, 256, 0, stream>>>(x, W_up, W_down, W_ln, b_ln,
                                          stats_p, c1, c2, wdp, wub);
    fused_main<<<512, 256, 0, stream>>>(x, wdp, wub, c1, c2, stats_p, out);
}